// Round 1
// baseline (878.459 us; speedup 1.0000x reference)
//
#include <hip/hip_runtime.h>
#include <math.h>

#define B_ 2
#define S_ 1024
#define D_ 512
#define H_ 8
#define P_ 16
#define DH_ 64
#define HP3_ 384
#define CONCAT_ 896
#define CUTOFF 15.0f
#define SCALE_ 0.125f   // DH^-0.5 = 1/8

// ---------------------------------------------------------------- reductions
__device__ __forceinline__ float waveReduceSum(float v) {
#pragma unroll
    for (int o = 32; o; o >>= 1) v += __shfl_down(v, o, 64);
    return v;
}
__device__ __forceinline__ float waveReduceMax(float v) {
#pragma unroll
    for (int o = 32; o; o >>= 1) v = fmaxf(v, __shfl_down(v, o, 64));
    return v;
}

// ---------------------------------------------------------------- kernel 1: LN(x) -> xn
__global__ __launch_bounds__(256) void ln1_kernel(
    const float* __restrict__ x, const float* __restrict__ g,
    const float* __restrict__ b, float* __restrict__ xn) {
    const int row = blockIdx.x;           // b*S + s  (2048 rows)
    const int t = threadIdx.x;
    const float* xr = x + row * D_;
    float x0 = xr[t], x1 = xr[t + 256];
    __shared__ float red[4];
    float s = waveReduceSum(x0 + x1);
    int lane = t & 63, wid = t >> 6;
    if (lane == 0) red[wid] = s;
    __syncthreads();
    float mean = (red[0] + red[1] + red[2] + red[3]) * (1.0f / D_);
    __syncthreads();
    float d0 = x0 - mean, d1 = x1 - mean;
    float v = waveReduceSum(d0 * d0 + d1 * d1);
    if (lane == 0) red[wid] = v;
    __syncthreads();
    float var = (red[0] + red[1] + red[2] + red[3]) * (1.0f / D_);
    float rs = rsqrtf(var + 1e-5f);
    xn[row * D_ + t]       = d0 * rs * g[t] + b[t];
    xn[row * D_ + t + 256] = d1 * rs * g[t + 256] + b[t + 256];
}

// ---------------------------------------------------------------- kernel 2: projections GEMM
// C = xn(2048x512) @ [Wq|Wk|Wv|Wqp|Wkp|Wvp] (512x2688), fused bias + coords epilogue.
// 64x64 tiles, BK=16, 256 threads, 4x4 microtile per thread.
__global__ __launch_bounds__(256) void proj_kernel(
    const float* __restrict__ xn, const float* __restrict__ coords,
    const float* __restrict__ Wq, const float* __restrict__ Wk, const float* __restrict__ Wv,
    const float* __restrict__ Wqp, const float* __restrict__ bqp,
    const float* __restrict__ Wkp, const float* __restrict__ bkp,
    const float* __restrict__ Wvp, const float* __restrict__ bvp,
    float* __restrict__ q, float* __restrict__ k, float* __restrict__ v,
    float* __restrict__ qp, float* __restrict__ kp, float* __restrict__ vp) {
    const int tid = threadIdx.x;
    const int rowBase = blockIdx.y * 64;
    const int colBase = blockIdx.x * 64;   // global col in [0,2688); segment-aligned (all bounds %64==0)

    const float* Wseg; int ldw, segBase, segId;
    if      (colBase < 512)  { Wseg = Wq;  ldw = D_;   segBase = 0;    segId = 0; }
    else if (colBase < 1024) { Wseg = Wk;  ldw = D_;   segBase = 512;  segId = 1; }
    else if (colBase < 1536) { Wseg = Wv;  ldw = D_;   segBase = 1024; segId = 2; }
    else if (colBase < 1920) { Wseg = Wqp; ldw = HP3_; segBase = 1536; segId = 3; }
    else if (colBase < 2304) { Wseg = Wkp; ldw = HP3_; segBase = 1920; segId = 4; }
    else                     { Wseg = Wvp; ldw = HP3_; segBase = 2304; segId = 5; }
    const int segc0 = colBase - segBase;

    __shared__ float As[16][65];
    __shared__ float Bs[16][64];
    const int tx = tid & 15, ty = tid >> 4;

    float acc[4][4];
#pragma unroll
    for (int i = 0; i < 4; i++)
#pragma unroll
        for (int j = 0; j < 4; j++) acc[i][j] = 0.f;

    for (int k0 = 0; k0 < D_; k0 += 16) {
#pragma unroll
        for (int i = 0; i < 4; i++) {
            int e = tid + i * 256;
            int r = e >> 4, kk = e & 15;
            As[kk][r] = xn[(rowBase + r) * D_ + k0 + kk];
            int c = e & 63, kb = e >> 6;
            Bs[kb][c] = Wseg[(k0 + kb) * ldw + segc0 + c];
        }
        __syncthreads();
#pragma unroll
        for (int kk = 0; kk < 16; kk++) {
            float a[4], bb[4];
#pragma unroll
            for (int i = 0; i < 4; i++) a[i] = As[kk][ty * 4 + i];
#pragma unroll
            for (int j = 0; j < 4; j++) bb[j] = Bs[kk][tx * 4 + j];
#pragma unroll
            for (int i = 0; i < 4; i++)
#pragma unroll
                for (int j = 0; j < 4; j++) acc[i][j] = fmaf(a[i], bb[j], acc[i][j]);
        }
        __syncthreads();
    }

#pragma unroll
    for (int i = 0; i < 4; i++) {
        int r = rowBase + ty * 4 + i;
#pragma unroll
        for (int j = 0; j < 4; j++) {
            int lc = segc0 + tx * 4 + j;
            float val = acc[i][j];
            switch (segId) {
                case 0: q[r * D_ + lc] = val; break;
                case 1: k[r * D_ + lc] = val; break;
                case 2: v[r * D_ + lc] = val; break;
                case 3: qp[r * HP3_ + lc] = val + bqp[lc] + coords[r * 3 + lc % 3]; break;
                case 4: kp[r * HP3_ + lc] = val + bkp[lc] + coords[r * 3 + lc % 3]; break;
                case 5: vp[r * HP3_ + lc] = val + bvp[lc]; break;
            }
        }
    }
}

// ---------------------------------------------------------------- kernel 3: kn2 = sum(kp^2) per (b,s,h)
__global__ __launch_bounds__(256) void kn2_kernel(
    const float* __restrict__ kp, float* __restrict__ kn2) {
    int idx = blockIdx.x * 256 + threadIdx.x;   // B*S*H = 16384
    const float* p = kp + idx * 48;             // (b,s,h) block of 48 is contiguous
    float s = 0.f;
#pragma unroll
    for (int i = 0; i < 48; i++) s = fmaf(p[i], p[i], s);
    kn2[idx] = s;
}

// ---------------------------------------------------------------- kernel 4: fused attention
// One block per (q-row, head, batch). Logits never touch HBM.
__global__ __launch_bounds__(256) void attn_kernel(
    const float* __restrict__ q, const float* __restrict__ k, const float* __restrict__ v,
    const float* __restrict__ qp, const float* __restrict__ kp, const float* __restrict__ vp,
    const float* __restrict__ kn2, const float* __restrict__ coords,
    const float* __restrict__ Wd1, const float* __restrict__ bd1,
    const float* __restrict__ Wd2, const float* __restrict__ bd2,
    float* __restrict__ attn_out) {
    const int qi = blockIdx.x, h = blockIdx.y, b = blockIdx.z;
    const int tid = threadIdx.x;
    const int rowQ = b * S_ + qi;

    __shared__ float sQ[64], sQP[48], sW1[32], sB1[32], sW2[32];
    __shared__ float sW[1024];
    __shared__ float red[4];
    __shared__ float sAcc[112];

    if (tid < 64)       sQ[tid] = q[rowQ * D_ + h * 64 + tid];
    else if (tid < 112) sQP[tid - 64] = qp[rowQ * HP3_ + h * 48 + (tid - 64)];
    else if (tid < 144) sW1[tid - 112] = Wd1[tid - 112];
    else if (tid < 176) sB1[tid - 144] = bd1[tid - 144];
    else if (tid < 208) sW2[tid - 176] = Wd2[(tid - 176) * H_ + h];
    const float cq0 = coords[rowQ * 3], cq1 = coords[rowQ * 3 + 1], cq2 = coords[rowQ * 3 + 2];
    const float bd2h = bd2[h];
    __syncthreads();

    float qn2 = 0.f;
#pragma unroll
    for (int i = 0; i < 48; i++) qn2 = fmaf(sQP[i], sQP[i], qn2);

    // phase 1: logits (4 keys per thread, register-resident)
    float logit[4];
    float m = -3.0e38f;
#pragma unroll
    for (int j = 0; j < 4; j++) {
        const int kk = tid + j * 256;
        const int rowK = b * S_ + kk;
        float dx = cq0 - coords[rowK * 3];
        float dy = cq1 - coords[rowK * 3 + 1];
        float dz = cq2 - coords[rowK * 3 + 2];
        float dist = sqrtf(dx * dx + dy * dy + dz * dz);
        float lg;
        if (dist < CUTOFF) {
            const float* kr = k + rowK * D_ + h * 64;
            float dot = 0.f;
#pragma unroll
            for (int i = 0; i < 64; i++) dot = fmaf(sQ[i], kr[i], dot);
            const float* kpr = kp + rowK * HP3_ + h * 48;
            float pd = 0.f;
#pragma unroll
            for (int i = 0; i < 48; i++) pd = fmaf(sQP[i], kpr[i], pd);
            float bias = bd2h;
#pragma unroll
            for (int i = 0; i < 32; i++) {
                float hd = fmaf(dist, sW1[i], sB1[i]);
                bias = fmaf(fmaxf(hd, 0.f), sW2[i], bias);
            }
            lg = SCALE_ * dot - 0.5f * (qn2 + kn2[rowK * H_ + h] - 2.f * pd) + bias;
        } else {
            lg = -1e9f;
        }
        logit[j] = lg;
        m = fmaxf(m, lg);
    }

    // phase 2: softmax (block max, exp, block sum)
    m = waveReduceMax(m);
    if ((tid & 63) == 0) red[tid >> 6] = m;
    __syncthreads();
    m = fmaxf(fmaxf(red[0], red[1]), fmaxf(red[2], red[3]));
    __syncthreads();
    float psum = 0.f;
#pragma unroll
    for (int j = 0; j < 4; j++) {
        float e = expf(logit[j] - m);
        sW[tid + j * 256] = e;
        psum += e;
    }
    psum = waveReduceSum(psum);
    if ((tid & 63) == 0) red[tid >> 6] = psum;
    __syncthreads();
    const float inv = 1.0f / (red[0] + red[1] + red[2] + red[3]);

    // phase 3: weighted sums. 2 groups of 128 threads split the 1024 keys;
    // within a group, thread d<64 does v dims, d in [64,112) does vp dims.
    const int g = tid >> 7, d = tid & 127;
    float acc = 0.f;
    if (d < 112) {
        const int k0 = g * 512;
        if (d < 64) {
            const float* vb = v + (size_t)(b * S_ + k0) * D_ + h * 64 + d;
            for (int kk = 0; kk < 512; kk++) acc = fmaf(sW[k0 + kk], vb[(size_t)kk * D_], acc);
        } else {
            const float* vb = vp + (size_t)(b * S_ + k0) * HP3_ + h * 48 + (d - 64);
            for (int kk = 0; kk < 512; kk++) acc = fmaf(sW[k0 + kk], vb[(size_t)kk * HP3_], acc);
        }
    }
    if (g == 1 && d < 112) sAcc[d] = acc;
    __syncthreads();
    if (g == 0 && d < 112) {
        float tot = (acc + sAcc[d]) * inv;
        float* outr = attn_out + (size_t)rowQ * CONCAT_;
        if (d < 64) outr[h * 64 + d] = tot;
        else        outr[512 + h * 48 + (d - 64)] = tot;
    }
}

// ---------------------------------------------------------------- kernel 5: out proj + residual + LN2 + coord update
__global__ __launch_bounds__(256) void out_kernel(
    const float* __restrict__ attn_out, const float* __restrict__ x,
    const float* __restrict__ coords,
    const float* __restrict__ Wo, const float* __restrict__ bo,
    const float* __restrict__ g2, const float* __restrict__ b2,
    float* __restrict__ out, float* __restrict__ coords_out) {
    const int row = blockIdx.x;    // b*S + s
    const int t = threadIdx.x;
    __shared__ float sIn[CONCAT_];
    __shared__ float red[4];
    __shared__ float credp[2][3];

    const float* ar = attn_out + (size_t)row * CONCAT_;
    sIn[t] = ar[t]; sIn[t + 256] = ar[t + 256]; sIn[t + 512] = ar[t + 512];
    if (t < 128) sIn[t + 768] = ar[t + 768];
    __syncthreads();

    // coord update: mean over (h,p) of ap[(h*16+p)*3 + dim]
    float c0 = 0.f, c1 = 0.f, c2 = 0.f;
    if (t < 128) { c0 = sIn[512 + t * 3]; c1 = sIn[512 + t * 3 + 1]; c2 = sIn[512 + t * 3 + 2]; }
#pragma unroll
    for (int o = 32; o; o >>= 1) {
        c0 += __shfl_down(c0, o, 64);
        c1 += __shfl_down(c1, o, 64);
        c2 += __shfl_down(c2, o, 64);
    }
    if (t < 128 && (t & 63) == 0) {
        credp[t >> 6][0] = c0; credp[t >> 6][1] = c1; credp[t >> 6][2] = c2;
    }
    __syncthreads();
    if (t < 3) {
        float s = credp[0][t] + credp[1][t];
        coords_out[row * 3 + t] = coords[row * 3 + t] + 0.1f * s * (1.0f / 128.f);
    }

    // output projection: each thread computes cols t and t+256
    float a0 = bo[t], a1 = bo[t + 256];
    for (int i = 0; i < CONCAT_; i++) {
        float xi = sIn[i];
        a0 = fmaf(xi, Wo[i * D_ + t], a0);
        a1 = fmaf(xi, Wo[i * D_ + t + 256], a1);
    }
    float y0 = x[(size_t)row * D_ + t] + a0;
    float y1 = x[(size_t)row * D_ + t + 256] + a1;

    // LN2
    float s = waveReduceSum(y0 + y1);
    int lane = t & 63, wid = t >> 6;
    if (lane == 0) red[wid] = s;
    __syncthreads();
    float mean = (red[0] + red[1] + red[2] + red[3]) * (1.0f / D_);
    __syncthreads();
    float d0 = y0 - mean, d1 = y1 - mean;
    float vv = waveReduceSum(d0 * d0 + d1 * d1);
    if (lane == 0) red[wid] = vv;
    __syncthreads();
    float var = (red[0] + red[1] + red[2] + red[3]) * (1.0f / D_);
    float rs = rsqrtf(var + 1e-5f);
    out[(size_t)row * D_ + t]       = d0 * rs * g2[t] + b2[t];
    out[(size_t)row * D_ + t + 256] = d1 * rs * g2[t + 256] + b2[t + 256];
}

// ---------------------------------------------------------------- launch
extern "C" void kernel_launch(void* const* d_in, const int* in_sizes, int n_in,
                              void* d_out, int out_size, void* d_ws, size_t ws_size,
                              hipStream_t stream) {
    const float* x      = (const float*)d_in[0];
    const float* coords = (const float*)d_in[1];
    const float* Wq     = (const float*)d_in[2];
    const float* Wk     = (const float*)d_in[3];
    const float* Wv     = (const float*)d_in[4];
    const float* Wqp    = (const float*)d_in[5];
    const float* bqp    = (const float*)d_in[6];
    const float* Wkp    = (const float*)d_in[7];
    const float* bkp    = (const float*)d_in[8];
    const float* Wvp    = (const float*)d_in[9];
    const float* bvp    = (const float*)d_in[10];
    const float* Wd1    = (const float*)d_in[11];
    const float* bd1    = (const float*)d_in[12];
    const float* Wd2    = (const float*)d_in[13];
    const float* bd2    = (const float*)d_in[14];
    const float* Wo     = (const float*)d_in[15];
    const float* bo     = (const float*)d_in[16];
    const float* g1     = (const float*)d_in[17];
    const float* b1     = (const float*)d_in[18];
    const float* g2     = (const float*)d_in[19];
    const float* b2     = (const float*)d_in[20];

    float* out        = (float*)d_out;                       // B*S*D
    float* coords_out = (float*)d_out + (size_t)B_ * S_ * D_; // B*S*3

    // ws layout (floats)
    float* ws = (float*)d_ws;
    const size_t NROW = (size_t)B_ * S_;        // 2048
    float* xn   = ws;                           // 2048*512
    float* q    = xn   + NROW * D_;
    float* k    = q    + NROW * D_;
    float* v    = k    + NROW * D_;
    float* qp   = v    + NROW * D_;             // 2048*384
    float* kp   = qp   + NROW * HP3_;
    float* vp   = kp   + NROW * HP3_;
    float* kn2  = vp   + NROW * HP3_;           // 2048*8
    float* aout = kn2  + NROW * H_;             // 2048*896

    ln1_kernel<<<NROW, 256, 0, stream>>>(x, g1, b1, xn);

    dim3 pgrid(2688 / 64, 2048 / 64);
    proj_kernel<<<pgrid, 256, 0, stream>>>(xn, coords, Wq, Wk, Wv,
                                           Wqp, bqp, Wkp, bkp, Wvp, bvp,
                                           q, k, v, qp, kp, vp);

    kn2_kernel<<<(NROW * H_) / 256, 256, 0, stream>>>(kp, kn2);

    dim3 agrid(S_, H_, B_);
    attn_kernel<<<agrid, 256, 0, stream>>>(q, k, v, qp, kp, vp, kn2, coords,
                                           Wd1, bd1, Wd2, bd2, aout);

    out_kernel<<<NROW, 256, 0, stream>>>(aout, x, coords, Wo, bo, g2, b2,
                                         out, coords_out);
}